// Round 15
// baseline (123.273 us; speedup 1.0000x reference)
//
#include <hip/hip_runtime.h>
#include <hip/hip_bf16.h>

typedef __bf16 bf16;
typedef bf16 bf16x8 __attribute__((ext_vector_type(8)));
typedef bf16 bf16x4 __attribute__((ext_vector_type(4)));
typedef float f32x4 __attribute__((ext_vector_type(4)));
typedef float f32x16 __attribute__((ext_vector_type(16)));
typedef unsigned int u32;
typedef u32 u32x4 __attribute__((ext_vector_type(4)));

#define S_LEN 2048
#define DM 1024
#define NH 16
#define DK 64
#define MTOK 4096  // B*S

// async global->LDS, 16B per lane; LDS dest is wave-uniform base + lane*16
__device__ __forceinline__ void gld16(const void* g, void* l) {
  __builtin_amdgcn_global_load_lds(
      (const __attribute__((address_space(1))) u32*)g,
      (__attribute__((address_space(3))) u32*)l, 16, 0, 0);
}

// pack two f32 -> u32 of two bf16 (compiler emits cvt_pk)
__device__ __forceinline__ u32 pkbf(float lo, float hi) {
  union { bf16 h[2]; u32 u; } c;
  c.h[0] = (bf16)lo; c.h[1] = (bf16)hi;
  return c.u;
}
// v_permlane32_swap_b32 a, b:  a_hi <-> b_lo (2x2 block transpose).
// Only used with DISTINCT operand values (equal-operand form is broken).
__device__ __forceinline__ void plswap(u32& a, u32& b) {
  asm volatile("v_permlane32_swap_b32 %0, %1" : "+v"(a), "+v"(b));
}

// ---------------------------------------------------------------- convert
__global__ __launch_bounds__(256) void cvt_all(
    const float* __restrict__ x, const float* __restrict__ wq, const float* __restrict__ wk,
    const float* __restrict__ wv, const float* __restrict__ wo,
    bf16* __restrict__ xb, bf16* __restrict__ wqb, bf16* __restrict__ wkb,
    bf16* __restrict__ wvb, bf16* __restrict__ wob) {
  const int i = blockIdx.x * blockDim.x + threadIdx.x;
  const int NX = (MTOK * DM) / 4;
  const int NW = (DM * DM) / 4;
  const float* src;
  bf16* dst;
  int off;
  if (i < NX) {
    src = x; dst = xb; off = i;
  } else {
    const int j = i - NX;
    const int w = j >> 18;
    off = j & (NW - 1);
    src = (w == 0) ? wq : (w == 1) ? wk : (w == 2) ? wv : wo;
    dst = (w == 0) ? wqb : (w == 1) ? wkb : (w == 2) ? wvb : wob;
  }
  f32x4 v = reinterpret_cast<const f32x4*>(src)[off];
  bf16x4 o;
  o[0] = (bf16)v[0]; o[1] = (bf16)v[1]; o[2] = (bf16)v[2]; o[3] = (bf16)v[3];
  reinterpret_cast<bf16x4*>(dst)[off] = o;
}

// ---------------------------------------------------------------- QKV GEMM
__global__ __launch_bounds__(256) void gemm_qkv(
    const bf16* __restrict__ A,
    const bf16* __restrict__ Wq, const bf16* __restrict__ Wk, const bf16* __restrict__ Wv,
    const float* __restrict__ Bq, const float* __restrict__ Bk, const float* __restrict__ Bv,
    bf16* __restrict__ Qo, bf16* __restrict__ Ko, bf16* __restrict__ Vt) {
  __shared__ char smem[65536];
  const int z = blockIdx.z;
  const bf16* W = (z == 0) ? Wq : (z == 1) ? Wk : Wv;
  const float* bias = (z == 0) ? Bq : (z == 1) ? Bk : Bv;
  const int m0 = blockIdx.y * 128;
  const int n0 = blockIdx.x * 128;
  const int tid = threadIdx.x;
  const int lane = tid & 63;
  const int wid = tid >> 6;
  const int wr = (wid >> 1) * 64, wc = (wid & 1) * 64;
  const int scb = 16 * ((lane & 7) ^ (lane >> 3));
  const int lr8 = lane >> 3;

  f32x4 acc[4][4] = {};

  auto STAGE = [&](int bi, int k0) {
#pragma unroll
    for (int c = 0; c < 4; ++c) {
      const int chunk = wid * 4 + c;
      const int row = chunk * 8 + lr8;
      gld16((const char*)A + ((size_t)(m0 + row) * DM + k0) * 2 + scb,
            smem + bi * 32768 + chunk * 1024);
      gld16((const char*)W + ((size_t)(n0 + row) * DM + k0) * 2 + scb,
            smem + bi * 32768 + 16384 + chunk * 1024);
    }
  };

  STAGE(0, 0);

  const int NK = DM / 64;  // 16
  for (int it = 0; it < NK; ++it) {
    if (it + 1 < NK) {
      STAGE((it + 1) & 1, (it + 1) * 64);
      asm volatile("s_waitcnt vmcnt(8)" ::: "memory");  // tile it resident
    } else {
      asm volatile("s_waitcnt vmcnt(0)" ::: "memory");
    }
    __builtin_amdgcn_s_barrier();
    asm volatile("" ::: "memory");
    const char* As = smem + (it & 1) * 32768;
    const char* Bs = As + 16384;
#pragma unroll
    for (int kk = 0; kk < 2; ++kk) {
      bf16x8 af[4], bfr[4];
#pragma unroll
      for (int i = 0; i < 4; ++i) {
        const int ar = wr + i * 16 + (lane & 15);
        af[i] = *reinterpret_cast<const bf16x8*>(
            As + ar * 128 + ((kk * 64 + 16 * (lane >> 4)) ^ ((ar & 7) << 4)));
        const int br = wc + i * 16 + (lane & 15);
        bfr[i] = *reinterpret_cast<const bf16x8*>(
            Bs + br * 128 + ((kk * 64 + 16 * (lane >> 4)) ^ ((br & 7) << 4)));
      }
      __builtin_amdgcn_s_setprio(1);
#pragma unroll
      for (int i = 0; i < 4; ++i)
#pragma unroll
        for (int j = 0; j < 4; ++j)
          acc[i][j] = __builtin_amdgcn_mfma_f32_16x16x32_bf16(af[i], bfr[j], acc[i][j], 0, 0, 0);
      __builtin_amdgcn_s_setprio(0);
    }
    asm volatile("" ::: "memory");
    __builtin_amdgcn_s_barrier();  // WAR: all waves done with buf (it&1)
  }

  // Q pre-scale: 1/sqrt(dk) * log2(e)  (attn softmax runs in exp2 domain)
  const float QSC = 0.125f * 1.44269504089f;
  const int bIdx = m0 >> 11;
  const int r4 = (lane >> 4) * 4;
#pragma unroll
  for (int i = 0; i < 4; ++i) {
    const int mrow = m0 + wr + i * 16 + r4;
    const int srow = mrow & (S_LEN - 1);
#pragma unroll
    for (int j = 0; j < 4; ++j) {
      const int n = n0 + wc + j * 16 + (lane & 15);
      const int h = n >> 6, d = n & 63;
      const int bh = bIdx * NH + h;
      const float bs = bias[n];
      if (z == 0) {
#pragma unroll
        for (int r = 0; r < 4; ++r)
          Qo[((size_t)bh * S_LEN + srow + r) * DK + d] = (bf16)((acc[i][j][r] + bs) * QSC);
      } else if (z == 1) {
#pragma unroll
        for (int r = 0; r < 4; ++r)
          Ko[((size_t)bh * S_LEN + srow + r) * DK + d] = (bf16)(acc[i][j][r] + bs);
      } else {
        bf16x4 pk;
#pragma unroll
        for (int r = 0; r < 4; ++r) pk[r] = (bf16)(acc[i][j][r] + bs);
        *reinterpret_cast<bf16x4*>(&Vt[((size_t)bh * DK + d) * S_LEN + srow]) = pk;
      }
    }
  }
}

// ---------------------------------------------------------------- attention
// (round-11 internals) 32x32 swapped-operand, QBLK=128 (4 waves x 32 q),
// KV-SPLIT-2, grid 1024, 3-buffer/1-barrier, counted vmcnt(4).
// NEW: work-balanced bid remap — 4 rounds of 256 blocks; each CU's four
// blocks sum to 34 tiles (was 48-4g: 48 vs 20 imbalance -> 1.41x makespan).
__global__ __launch_bounds__(256) void attn_fwd(
    const bf16* __restrict__ Q, const bf16* __restrict__ K,
    const bf16* __restrict__ Vt,
    bf16* __restrict__ O0p, bf16* __restrict__ O1p,
    float* __restrict__ L0, float* __restrict__ M0,
    float* __restrict__ L1, float* __restrict__ M1) {
  __shared__ char smem[49152];  // buf i<3: K at i*16384 (8KB), V at +8192 (8KB)

  const int bid = blockIdx.x;
  const int grp = bid >> 8;        // 0..3
  const int c = bid & 255;
  const int half = grp >> 1;       // rounds 0,1 -> half 0; rounds 2,3 -> half 1
  const int qt = (grp & 1) ? (c >> 5) : 15 - (c >> 5);  // desc 15..8, then asc 0..7
  const int bh = c & 31;
  const int tid = threadIdx.x, lane = tid & 63, wid = tid >> 6;
  const int q0 = qt * 128;
  const int scb = 16 * ((lane & 7) ^ (lane >> 3));
  const int l31 = lane & 31;
  const int hi = lane >> 5;
  const int qrow = q0 + wid * 32 + l31;
  const int swz = (l31 & 7) << 4;

  // Q fragments: B-operand of mfma32 (col=q, k = 16*ks + 8*hi + j)
  const bf16* qb = Q + ((size_t)bh * S_LEN + qrow) * DK;
  bf16x8 qf[4];
#pragma unroll
  for (int ks = 0; ks < 4; ++ks)
    qf[ks] = *reinterpret_cast<const bf16x8*>(qb + ks * 16 + 8 * hi);

  f32x16 o0 = {}, o1 = {};  // O^T: row d = (r&3)+8*(r>>2)+4*hi (+32*dt), col q = l31
  float m_r = -3.0e38f, l_r = 0.f;

  const int t0 = half * (qt + 1);
  const int t1 = t0 + qt + 1;
  const int tdiag = 2 * qt;  // tiles >= tdiag need causal masking

  auto STAGE = [&](int bi, int t) {
    const int kv0 = t * 64;
#pragma unroll
    for (int c2 = 0; c2 < 2; ++c2) {
      const int chunk = wid * 2 + c2;  // 8 chunks x 1KB each for K and V
      const int row = chunk * 8 + (lane >> 3);
      gld16((const char*)K + ((size_t)(bh * S_LEN + kv0 + row)) * 128 + scb,
            smem + bi * 16384 + chunk * 1024);
      gld16((const char*)Vt + ((size_t)(bh * DK + row)) * (S_LEN * 2) + (size_t)kv0 * 2 + scb,
            smem + bi * 16384 + 8192 + chunk * 1024);
    }
  };

  STAGE(t0 % 3, t0);

  for (int t = t0; t < t1; ++t) {
    const int kv0 = t * 64;
    if (t + 1 < t1) {
      STAGE((t + 1) % 3, t + 1);
      asm volatile("s_waitcnt vmcnt(4)" ::: "memory");
    } else {
      asm volatile("s_waitcnt vmcnt(0)" ::: "memory");
    }
    __builtin_amdgcn_s_barrier();
    asm volatile("" ::: "memory");
    const char* Kc = smem + (t % 3) * 16384;
    const char* Vc = Kc + 8192;

    // ---- S^T = K Q^T : per lane one query (l31), keys crow(r,hi)+32*kt
    f32x16 s0 = {}, s1 = {};
#pragma unroll
    for (int kt = 0; kt < 2; ++kt) {
      bf16x8 ka[4];
#pragma unroll
      for (int ks = 0; ks < 4; ++ks)
        ka[ks] = *reinterpret_cast<const bf16x8*>(
            Kc + (kt * 32 + l31) * 128 + ((ks * 32 + 16 * hi) ^ swz));
      f32x16& sd = kt ? s1 : s0;
      __builtin_amdgcn_s_setprio(1);
#pragma unroll
      for (int ks = 0; ks < 4; ++ks)
        sd = __builtin_amdgcn_mfma_f32_32x32x16_bf16(ka[ks], qf[ks], sd, 0, 0, 0);
      __builtin_amdgcn_s_setprio(0);
    }

    if (t >= tdiag) {  // diagonal tiles: causal mask
#pragma unroll
      for (int r = 0; r < 16; ++r) {
        const int key0 = kv0 + (r & 3) + 8 * (r >> 2) + 4 * hi;
        if (key0 > qrow) s0[r] = -1.0e9f;
        if (key0 + 32 > qrow) s1[r] = -1.0e9f;
      }
    }

    // ---- in-register softmax (exp2 domain, defer-max THR=8, tree reduce)
    float tmax[16];
#pragma unroll
    for (int r = 0; r < 16; ++r) tmax[r] = fmaxf(s0[r], s1[r]);
#pragma unroll
    for (int w = 8; w >= 1; w >>= 1)
#pragma unroll
      for (int r = 0; r < w; ++r) tmax[r] = fmaxf(tmax[r], tmax[r + w]);
    const float mx = fmaxf(tmax[0], __shfl_xor(tmax[0], 32));
    if (!__all(mx <= m_r + 8.f)) {
      const float nm = fmaxf(m_r, mx);
      const float sc = exp2f(m_r - nm);
      l_r *= sc;
      o0 *= sc;
      o1 *= sc;
      m_r = nm;
    }
    float ts[16];
#pragma unroll
    for (int r = 0; r < 16; ++r) {
      s0[r] = exp2f(s0[r] - m_r);
      s1[r] = exp2f(s1[r] - m_r);
      ts[r] = s0[r] + s1[r];
    }
#pragma unroll
    for (int w = 8; w >= 1; w >>= 1)
#pragma unroll
      for (int r = 0; r < w; ++r) ts[r] += ts[r + w];
    l_r += ts[0] + __shfl_xor(ts[0], 32);

    // ---- pack P^T B-operand fragments: pb[ks] elem j <-> key 16*ks+8*hi+j
    bf16x8 pb[4];
#pragma unroll
    for (int kt = 0; kt < 2; ++kt) {
      const f32x16& p = kt ? s1 : s0;
#pragma unroll
      for (int s2 = 0; s2 < 2; ++s2) {
        u32 cA = pkbf(p[8 * s2 + 0], p[8 * s2 + 1]);
        u32 cB = pkbf(p[8 * s2 + 2], p[8 * s2 + 3]);
        u32 cC = pkbf(p[8 * s2 + 4], p[8 * s2 + 5]);
        u32 cD = pkbf(p[8 * s2 + 6], p[8 * s2 + 7]);
        plswap(cA, cC);
        plswap(cB, cD);
        u32x4 w;
        w[0] = cA; w[1] = cB; w[2] = cC; w[3] = cD;
        pb[kt * 2 + s2] = __builtin_bit_cast(bf16x8, w);
      }
    }

    // ---- O^T += V^T P^T  (A row = d, from Vs[d][kv]; B col = q)
#pragma unroll
    for (int dt = 0; dt < 2; ++dt) {
      bf16x8 va[4];
#pragma unroll
      for (int ks = 0; ks < 4; ++ks)
        va[ks] = *reinterpret_cast<const bf16x8*>(
            Vc + (dt * 32 + l31) * 128 + ((ks * 32 + 16 * hi) ^ swz));
      f32x16& od = dt ? o1 : o0;
      __builtin_amdgcn_s_setprio(1);
#pragma unroll
      for (int ks = 0; ks < 4; ++ks)
        od = __builtin_amdgcn_mfma_f32_32x32x16_bf16(va[ks], pb[ks], od, 0, 0, 0);
      __builtin_amdgcn_s_setprio(0);
    }
    // no trailing barrier: 3-buffer rotation makes next STAGE safe
  }

  // ---- write unnormalized partial O + (l,m); merge kernel normalizes
  const int b = bh >> 4, h = bh & 15;
  bf16* Opart = half ? O1p : O0p;
  bf16* obase = Opart + ((size_t)(b * S_LEN + qrow)) * DM + h * DK;
#pragma unroll
  for (int dt = 0; dt < 2; ++dt) {
    const f32x16& od = dt ? o1 : o0;
#pragma unroll
    for (int g = 0; g < 4; ++g) {
      bf16x4 pk4;
#pragma unroll
      for (int m = 0; m < 4; ++m) pk4[m] = (bf16)od[4 * g + m];
      *reinterpret_cast<bf16x4*>(obase + dt * 32 + 8 * g + 4 * hi) = pk4;
    }
  }
  const int lmi = bh * S_LEN + qrow;  // lanes l31 / l31+32 write same value
  if (half) { L1[lmi] = l_r; M1[lmi] = m_r; }
  else      { L0[lmi] = l_r; M0[lmi] = m_r; }
}

// ---------------------------------------------------------------- merge
// AO = (a0*O0 + a1*O1) / (a0*l0 + a1*l1),  a_i = exp2(m_i - max(m0,m1))
__global__ __launch_bounds__(256) void attn_merge(
    const bf16* __restrict__ O0, const bf16* __restrict__ O1,
    const float* __restrict__ L0, const float* __restrict__ M0,
    const float* __restrict__ L1, const float* __restrict__ M1,
    bf16* __restrict__ AO) {
  const int i = blockIdx.x * blockDim.x + threadIdx.x;
  const int e = i * 8;                // 8 bf16 per thread, within one head
  const int row = e >> 10;            // token 0..4095
  const int b = row >> 11, s = row & 2047;
  const int h = (e >> 6) & 15;
  const int lmi = (b * NH + h) * S_LEN + s;
  const float m0 = M0[lmi], m1 = M1[lmi];
  const float m = fmaxf(m0, m1);
  const float a0 = exp2f(m0 - m), a1 = exp2f(m1 - m);
  const float inv = 1.0f / (a0 * L0[lmi] + a1 * L1[lmi]);
  const float f0 = a0 * inv, f1 = a1 * inv;
  bf16x8 v0 = *reinterpret_cast<const bf16x8*>(O0 + e);
  bf16x8 v1 = *reinterpret_cast<const bf16x8*>(O1 + e);
  bf16x8 o;
#pragma unroll
  for (int j = 0; j < 8; ++j)
    o[j] = (bf16)(f0 * (float)v0[j] + f1 * (float)v1[j]);
  *reinterpret_cast<bf16x8*>(AO + e) = o;
}

// ---------------------------------------------------------------- out proj
__global__ __launch_bounds__(256) void gemm_out(
    const bf16* __restrict__ A, const bf16* __restrict__ W,
    const float* __restrict__ bias, float* __restrict__ C) {
  __shared__ char smem[65536];
  const int m0 = blockIdx.y * 128, n0 = blockIdx.x * 128;
  const int tid = threadIdx.x, lane = tid & 63, wid = tid >> 6;
  const int wr = (wid >> 1) * 64, wc = (wid & 1) * 64;
  const int scb = 16 * ((lane & 7) ^ (lane >> 3));
  const int lr8 = lane >> 3;
  f32x4 acc[4][4] = {};

  auto STAGE = [&](int bi, int k0) {
#pragma unroll
    for (int c = 0; c < 4; ++c) {
      const int chunk = wid * 4 + c;
      const int row = chunk * 8 + lr8;
      gld16((const char*)A + ((size_t)(m0 + row) * DM + k0) * 2 + scb,
            smem + bi * 32768 + chunk * 1024);
      gld16((const char*)W + ((size_t)(n0 + row) * DM + k0) * 2 + scb,
            smem + bi * 32768 + 16384 + chunk * 1024);
    }
  };

  STAGE(0, 0);

  const int NK = DM / 64;
  for (int it = 0; it < NK; ++it) {
    if (it + 1 < NK) {
      STAGE((it + 1) & 1, (it + 1) * 64);
      asm volatile("s_waitcnt vmcnt(8)" ::: "memory");
    } else {
      asm volatile("s_waitcnt vmcnt(0)" ::: "memory");
    }
    __builtin_amdgcn_s_barrier();
    asm volatile("" ::: "memory");
    const char* As = smem + (it & 1) * 32768;
    const char* Bs = As + 16384;
#pragma unroll
    for (int kk = 0; kk < 2; ++kk) {
      bf16x8 af[4], bfr[4];
#pragma unroll
      for (int i = 0; i < 4; ++i) {
        const int ar = wr + i * 16 + (lane & 15);
        af[i] = *reinterpret_cast<const bf16x8*>(
            As + ar * 128 + ((kk * 64 + 16 * (lane >> 4)) ^ ((ar & 7) << 4)));
        const int br = wc + i * 16 + (lane & 15);
        bfr[i] = *reinterpret_cast<const bf16x8*>(
            Bs + br * 128 + ((kk * 64 + 16 * (lane >> 4)) ^ ((br & 7) << 4)));
      }
      __builtin_amdgcn_s_setprio(1);
#pragma unroll
      for (int i = 0; i < 4; ++i)
#pragma unroll
        for (int j = 0; j < 4; ++j)
          acc[i][j] = __builtin_amdgcn_mfma_f32_16x16x32_bf16(af[i], bfr[j], acc[i][j], 0, 0, 0);
      __builtin_amdgcn_s_setprio(0);
    }
    asm volatile("" ::: "memory");
    __builtin_amdgcn_s_barrier();
  }

  const int r4 = (lane >> 4) * 4;
#pragma unroll
  for (int i = 0; i < 4; ++i) {
    const int mrow = m0 + wr + i * 16 + r4;
#pragma unroll
    for (int j = 0; j < 4; ++j) {
      const int n = n0 + wc + j * 16 + (lane & 15);
      const float bs = bias[n];
#pragma unroll
      for (int r = 0; r < 4; ++r) C[(size_t)(mrow + r) * DM + n] = acc[i][j][r] + bs;
    }
  }
}

// ---------------------------------------------------------------- launcher
extern "C" void kernel_launch(void* const* d_in, const int* in_sizes, int n_in,
                              void* d_out, int out_size, void* d_ws, size_t ws_size,
                              hipStream_t stream) {
  const float* x = (const float*)d_in[0];
  const float* Wq = (const float*)d_in[2];
  const float* bq = (const float*)d_in[3];
  const float* Wk = (const float*)d_in[4];
  const float* bk = (const float*)d_in[5];
  const float* Wv = (const float*)d_in[6];
  const float* bv = (const float*)d_in[7];
  const float* Wo = (const float*)d_in[8];
  const float* bo = (const float*)d_in[9];

  char* ws = (char*)d_ws;  // 48 MB total, regions reused across phases
  bf16* xb  = (bf16*)(ws);
  bf16* wqb = (bf16*)(ws + (8u << 20));
  bf16* wkb = (bf16*)(ws + (10u << 20));
  bf16* wvb = (bf16*)(ws + (12u << 20));
  bf16* wob = (bf16*)(ws + (14u << 20));
  bf16* Qw  = (bf16*)(ws + (16u << 20));
  bf16* Kw  = (bf16*)(ws + (24u << 20));
  bf16* Vtw = (bf16*)(ws + (32u << 20));
  bf16* AO  = (bf16*)(ws + (40u << 20));

  // attn partial buffers (reuse dead regions):
  bf16* O0p = (bf16*)(ws);                         // 8MB in xb slot
  bf16* O1p = AO;                                  // 8MB in AO slot (merged in place)
  float* L0 = (float*)(ws + (8u << 20));           // 256KB each, in wqb slot
  float* M0 = (float*)(ws + (8u << 20) + 262144);
  float* L1 = (float*)(ws + (8u << 20) + 524288);
  float* M1 = (float*)(ws + (8u << 20) + 786432);

  cvt_all<<<8192, 256, 0, stream>>>(x, Wq, Wk, Wv, Wo, xb, wqb, wkb, wvb, wob);

  gemm_qkv<<<dim3(DM / 128, MTOK / 128, 3), 256, 0, stream>>>(
      xb, wqb, wkb, wvb, bq, bk, bv, Qw, Kw, Vtw);
  attn_fwd<<<dim3(1024), 256, 0, stream>>>(Qw, Kw, Vtw, O0p, O1p, L0, M0, L1, M1);
  attn_merge<<<dim3(2048), 256, 0, stream>>>(O0p, O1p, L0, M0, L1, M1, AO);
  gemm_out<<<dim3(DM / 128, MTOK / 128), 256, 0, stream>>>(AO, wob, bo, (float*)d_out);
}

// Round 16
// 118.840 us; speedup vs baseline: 1.0373x; 1.0373x over previous
//
#include <hip/hip_runtime.h>
#include <hip/hip_bf16.h>

typedef __bf16 bf16;
typedef bf16 bf16x8 __attribute__((ext_vector_type(8)));
typedef bf16 bf16x4 __attribute__((ext_vector_type(4)));
typedef float f32x4 __attribute__((ext_vector_type(4)));
typedef float f32x16 __attribute__((ext_vector_type(16)));
typedef unsigned int u32;
typedef u32 u32x4 __attribute__((ext_vector_type(4)));

#define S_LEN 2048
#define DM 1024
#define NH 16
#define DK 64
#define MTOK 4096  // B*S

// async global->LDS, 16B per lane; LDS dest is wave-uniform base + lane*16
__device__ __forceinline__ void gld16(const void* g, void* l) {
  __builtin_amdgcn_global_load_lds(
      (const __attribute__((address_space(1))) u32*)g,
      (__attribute__((address_space(3))) u32*)l, 16, 0, 0);
}

// pack two f32 -> u32 of two bf16 (compiler emits cvt_pk)
__device__ __forceinline__ u32 pkbf(float lo, float hi) {
  union { bf16 h[2]; u32 u; } c;
  c.h[0] = (bf16)lo; c.h[1] = (bf16)hi;
  return c.u;
}
// v_permlane32_swap_b32 a, b:  a_hi <-> b_lo (2x2 block transpose).
// Only used with DISTINCT operand values (equal-operand form is broken).
__device__ __forceinline__ void plswap(u32& a, u32& b) {
  asm volatile("v_permlane32_swap_b32 %0, %1" : "+v"(a), "+v"(b));
}

// ---------------------------------------------------------------- convert
__global__ __launch_bounds__(256) void cvt_all(
    const float* __restrict__ x, const float* __restrict__ wq, const float* __restrict__ wk,
    const float* __restrict__ wv, const float* __restrict__ wo,
    bf16* __restrict__ xb, bf16* __restrict__ wqb, bf16* __restrict__ wkb,
    bf16* __restrict__ wvb, bf16* __restrict__ wob) {
  const int i = blockIdx.x * blockDim.x + threadIdx.x;
  const int NX = (MTOK * DM) / 4;
  const int NW = (DM * DM) / 4;
  const float* src;
  bf16* dst;
  int off;
  if (i < NX) {
    src = x; dst = xb; off = i;
  } else {
    const int j = i - NX;
    const int w = j >> 18;
    off = j & (NW - 1);
    src = (w == 0) ? wq : (w == 1) ? wk : (w == 2) ? wv : wo;
    dst = (w == 0) ? wqb : (w == 1) ? wkb : (w == 2) ? wvb : wob;
  }
  f32x4 v = reinterpret_cast<const f32x4*>(src)[off];
  bf16x4 o;
  o[0] = (bf16)v[0]; o[1] = (bf16)v[1]; o[2] = (bf16)v[2]; o[3] = (bf16)v[3];
  reinterpret_cast<bf16x4*>(dst)[off] = o;
}

// ---------------------------------------------------------------- QKV GEMM
__global__ __launch_bounds__(256) void gemm_qkv(
    const bf16* __restrict__ A,
    const bf16* __restrict__ Wq, const bf16* __restrict__ Wk, const bf16* __restrict__ Wv,
    const float* __restrict__ Bq, const float* __restrict__ Bk, const float* __restrict__ Bv,
    bf16* __restrict__ Qo, bf16* __restrict__ Ko, bf16* __restrict__ Vt) {
  __shared__ char smem[65536];
  const int z = blockIdx.z;
  const bf16* W = (z == 0) ? Wq : (z == 1) ? Wk : Wv;
  const float* bias = (z == 0) ? Bq : (z == 1) ? Bk : Bv;
  const int m0 = blockIdx.y * 128;
  const int n0 = blockIdx.x * 128;
  const int tid = threadIdx.x;
  const int lane = tid & 63;
  const int wid = tid >> 6;
  const int wr = (wid >> 1) * 64, wc = (wid & 1) * 64;
  const int scb = 16 * ((lane & 7) ^ (lane >> 3));
  const int lr8 = lane >> 3;

  f32x4 acc[4][4] = {};

  auto STAGE = [&](int bi, int k0) {
#pragma unroll
    for (int c = 0; c < 4; ++c) {
      const int chunk = wid * 4 + c;
      const int row = chunk * 8 + lr8;
      gld16((const char*)A + ((size_t)(m0 + row) * DM + k0) * 2 + scb,
            smem + bi * 32768 + chunk * 1024);
      gld16((const char*)W + ((size_t)(n0 + row) * DM + k0) * 2 + scb,
            smem + bi * 32768 + 16384 + chunk * 1024);
    }
  };

  STAGE(0, 0);

  const int NK = DM / 64;  // 16
  for (int it = 0; it < NK; ++it) {
    if (it + 1 < NK) {
      STAGE((it + 1) & 1, (it + 1) * 64);
      asm volatile("s_waitcnt vmcnt(8)" ::: "memory");  // tile it resident
    } else {
      asm volatile("s_waitcnt vmcnt(0)" ::: "memory");
    }
    __builtin_amdgcn_s_barrier();
    asm volatile("" ::: "memory");
    const char* As = smem + (it & 1) * 32768;
    const char* Bs = As + 16384;
#pragma unroll
    for (int kk = 0; kk < 2; ++kk) {
      bf16x8 af[4], bfr[4];
#pragma unroll
      for (int i = 0; i < 4; ++i) {
        const int ar = wr + i * 16 + (lane & 15);
        af[i] = *reinterpret_cast<const bf16x8*>(
            As + ar * 128 + ((kk * 64 + 16 * (lane >> 4)) ^ ((ar & 7) << 4)));
        const int br = wc + i * 16 + (lane & 15);
        bfr[i] = *reinterpret_cast<const bf16x8*>(
            Bs + br * 128 + ((kk * 64 + 16 * (lane >> 4)) ^ ((br & 7) << 4)));
      }
      __builtin_amdgcn_s_setprio(1);
#pragma unroll
      for (int i = 0; i < 4; ++i)
#pragma unroll
        for (int j = 0; j < 4; ++j)
          acc[i][j] = __builtin_amdgcn_mfma_f32_16x16x32_bf16(af[i], bfr[j], acc[i][j], 0, 0, 0);
      __builtin_amdgcn_s_setprio(0);
    }
    asm volatile("" ::: "memory");
    __builtin_amdgcn_s_barrier();  // WAR: all waves done with buf (it&1)
  }

  // Q pre-scale: 1/sqrt(dk) * log2(e)  (attn softmax runs in exp2 domain)
  const float QSC = 0.125f * 1.44269504089f;
  const int bIdx = m0 >> 11;
  const int r4 = (lane >> 4) * 4;
#pragma unroll
  for (int i = 0; i < 4; ++i) {
    const int mrow = m0 + wr + i * 16 + r4;
    const int srow = mrow & (S_LEN - 1);
#pragma unroll
    for (int j = 0; j < 4; ++j) {
      const int n = n0 + wc + j * 16 + (lane & 15);
      const int h = n >> 6, d = n & 63;
      const int bh = bIdx * NH + h;
      const float bs = bias[n];
      if (z == 0) {
#pragma unroll
        for (int r = 0; r < 4; ++r)
          Qo[((size_t)bh * S_LEN + srow + r) * DK + d] = (bf16)((acc[i][j][r] + bs) * QSC);
      } else if (z == 1) {
#pragma unroll
        for (int r = 0; r < 4; ++r)
          Ko[((size_t)bh * S_LEN + srow + r) * DK + d] = (bf16)(acc[i][j][r] + bs);
      } else {
        bf16x4 pk;
#pragma unroll
        for (int r = 0; r < 4; ++r) pk[r] = (bf16)(acc[i][j][r] + bs);
        *reinterpret_cast<bf16x4*>(&Vt[((size_t)bh * DK + d) * S_LEN + srow]) = pk;
      }
    }
  }
}

// ---------------------------------------------------------------- attention
// (round-11 internals) 32x32 swapped-operand, QBLK=128 (4 waves x 32 q),
// KV-SPLIT-2, grid 1024. NEW: 2-buffer LDS (32KB -> 5 blocks/CU residency,
// was 3x16KB=48KB -> 3 blocks/CU). Loop order per tile:
//   vmcnt(0) [own tile-t loads done] ; s_barrier [all waves' loads visible +
//   all finished compute(t-1)] ; STAGE(t+1) [overwrites buf of t-1, now safe]
//   ; compute(t).  Single barrier, race-free with 2 buffers.
__global__ __launch_bounds__(256) void attn_fwd(
    const bf16* __restrict__ Q, const bf16* __restrict__ K,
    const bf16* __restrict__ Vt,
    bf16* __restrict__ O0p, bf16* __restrict__ O1p,
    float* __restrict__ L0, float* __restrict__ M0,
    float* __restrict__ L1, float* __restrict__ M1) {
  __shared__ char smem[32768];  // buf i<2: K at i*16384 (8KB), V at +8192 (8KB)

  const int bid = blockIdx.x;
  const int half = bid >> 9;
  const int sub = bid & 511;
  const int qt = 15 - (sub >> 5);  // heavy q-tiles first
  const int bh = sub & 31;
  const int tid = threadIdx.x, lane = tid & 63, wid = tid >> 6;
  const int q0 = qt * 128;
  const int scb = 16 * ((lane & 7) ^ (lane >> 3));
  const int l31 = lane & 31;
  const int hi = lane >> 5;
  const int qrow = q0 + wid * 32 + l31;
  const int swz = (l31 & 7) << 4;

  // Q fragments: B-operand of mfma32 (col=q, k = 16*ks + 8*hi + j)
  const bf16* qb = Q + ((size_t)bh * S_LEN + qrow) * DK;
  bf16x8 qf[4];
#pragma unroll
  for (int ks = 0; ks < 4; ++ks)
    qf[ks] = *reinterpret_cast<const bf16x8*>(qb + ks * 16 + 8 * hi);

  f32x16 o0 = {}, o1 = {};  // O^T: row d = (r&3)+8*(r>>2)+4*hi (+32*dt), col q = l31
  float m_r = -3.0e38f, l_r = 0.f;

  const int t0 = half * (qt + 1);
  const int t1 = t0 + qt + 1;
  const int tdiag = 2 * qt;  // tiles >= tdiag need causal masking

  auto STAGE = [&](int bi, int t) {
    const int kv0 = t * 64;
#pragma unroll
    for (int c2 = 0; c2 < 2; ++c2) {
      const int chunk = wid * 2 + c2;  // 8 chunks x 1KB each for K and V
      const int row = chunk * 8 + (lane >> 3);
      gld16((const char*)K + ((size_t)(bh * S_LEN + kv0 + row)) * 128 + scb,
            smem + bi * 16384 + chunk * 1024);
      gld16((const char*)Vt + ((size_t)(bh * DK + row)) * (S_LEN * 2) + (size_t)kv0 * 2 + scb,
            smem + bi * 16384 + 8192 + chunk * 1024);
    }
  };

  STAGE(t0 & 1, t0);

  for (int t = t0; t < t1; ++t) {
    const int kv0 = t * 64;
    asm volatile("s_waitcnt vmcnt(0)" ::: "memory");  // own tile-t loads done
    __builtin_amdgcn_s_barrier();  // all loads visible; all done with buf (t-1)
    asm volatile("" ::: "memory");
    if (t + 1 < t1) STAGE((t + 1) & 1, t + 1);
    const char* Kc = smem + (t & 1) * 16384;
    const char* Vc = Kc + 8192;

    // ---- S^T = K Q^T : per lane one query (l31), keys crow(r,hi)+32*kt
    f32x16 s0 = {}, s1 = {};
#pragma unroll
    for (int kt = 0; kt < 2; ++kt) {
      bf16x8 ka[4];
#pragma unroll
      for (int ks = 0; ks < 4; ++ks)
        ka[ks] = *reinterpret_cast<const bf16x8*>(
            Kc + (kt * 32 + l31) * 128 + ((ks * 32 + 16 * hi) ^ swz));
      f32x16& sd = kt ? s1 : s0;
      __builtin_amdgcn_s_setprio(1);
#pragma unroll
      for (int ks = 0; ks < 4; ++ks)
        sd = __builtin_amdgcn_mfma_f32_32x32x16_bf16(ka[ks], qf[ks], sd, 0, 0, 0);
      __builtin_amdgcn_s_setprio(0);
    }

    if (t >= tdiag) {  // diagonal tiles: causal mask
#pragma unroll
      for (int r = 0; r < 16; ++r) {
        const int key0 = kv0 + (r & 3) + 8 * (r >> 2) + 4 * hi;
        if (key0 > qrow) s0[r] = -1.0e9f;
        if (key0 + 32 > qrow) s1[r] = -1.0e9f;
      }
    }

    // ---- in-register softmax (exp2 domain, defer-max THR=8, tree reduce)
    float tmax[16];
#pragma unroll
    for (int r = 0; r < 16; ++r) tmax[r] = fmaxf(s0[r], s1[r]);
#pragma unroll
    for (int w = 8; w >= 1; w >>= 1)
#pragma unroll
      for (int r = 0; r < w; ++r) tmax[r] = fmaxf(tmax[r], tmax[r + w]);
    const float mx = fmaxf(tmax[0], __shfl_xor(tmax[0], 32));
    if (!__all(mx <= m_r + 8.f)) {
      const float nm = fmaxf(m_r, mx);
      const float sc = exp2f(m_r - nm);
      l_r *= sc;
      o0 *= sc;
      o1 *= sc;
      m_r = nm;
    }
    float ts[16];
#pragma unroll
    for (int r = 0; r < 16; ++r) {
      s0[r] = exp2f(s0[r] - m_r);
      s1[r] = exp2f(s1[r] - m_r);
      ts[r] = s0[r] + s1[r];
    }
#pragma unroll
    for (int w = 8; w >= 1; w >>= 1)
#pragma unroll
      for (int r = 0; r < w; ++r) ts[r] += ts[r + w];
    l_r += ts[0] + __shfl_xor(ts[0], 32);

    // ---- pack P^T B-operand fragments: pb[ks] elem j <-> key 16*ks+8*hi+j
    bf16x8 pb[4];
#pragma unroll
    for (int kt = 0; kt < 2; ++kt) {
      const f32x16& p = kt ? s1 : s0;
#pragma unroll
      for (int s2 = 0; s2 < 2; ++s2) {
        u32 cA = pkbf(p[8 * s2 + 0], p[8 * s2 + 1]);
        u32 cB = pkbf(p[8 * s2 + 2], p[8 * s2 + 3]);
        u32 cC = pkbf(p[8 * s2 + 4], p[8 * s2 + 5]);
        u32 cD = pkbf(p[8 * s2 + 6], p[8 * s2 + 7]);
        plswap(cA, cC);
        plswap(cB, cD);
        u32x4 w;
        w[0] = cA; w[1] = cB; w[2] = cC; w[3] = cD;
        pb[kt * 2 + s2] = __builtin_bit_cast(bf16x8, w);
      }
    }

    // ---- O^T += V^T P^T  (A row = d, from Vs[d][kv]; B col = q)
#pragma unroll
    for (int dt = 0; dt < 2; ++dt) {
      bf16x8 va[4];
#pragma unroll
      for (int ks = 0; ks < 4; ++ks)
        va[ks] = *reinterpret_cast<const bf16x8*>(
            Vc + (dt * 32 + l31) * 128 + ((ks * 32 + 16 * hi) ^ swz));
      f32x16& od = dt ? o1 : o0;
      __builtin_amdgcn_s_setprio(1);
#pragma unroll
      for (int ks = 0; ks < 4; ++ks)
        od = __builtin_amdgcn_mfma_f32_32x32x16_bf16(va[ks], pb[ks], od, 0, 0, 0);
      __builtin_amdgcn_s_setprio(0);
    }
  }

  // ---- write unnormalized partial O + (l,m); merge kernel normalizes
  const int b = bh >> 4, h = bh & 15;
  bf16* Opart = half ? O1p : O0p;
  bf16* obase = Opart + ((size_t)(b * S_LEN + qrow)) * DM + h * DK;
#pragma unroll
  for (int dt = 0; dt < 2; ++dt) {
    const f32x16& od = dt ? o1 : o0;
#pragma unroll
    for (int g = 0; g < 4; ++g) {
      bf16x4 pk4;
#pragma unroll
      for (int m = 0; m < 4; ++m) pk4[m] = (bf16)od[4 * g + m];
      *reinterpret_cast<bf16x4*>(obase + dt * 32 + 8 * g + 4 * hi) = pk4;
    }
  }
  const int lmi = bh * S_LEN + qrow;  // lanes l31 / l31+32 write same value
  if (half) { L1[lmi] = l_r; M1[lmi] = m_r; }
  else      { L0[lmi] = l_r; M0[lmi] = m_r; }
}

// ---------------------------------------------------------------- merge
// AO = (a0*O0 + a1*O1) / (a0*l0 + a1*l1),  a_i = exp2(m_i - max(m0,m1))
__global__ __launch_bounds__(256) void attn_merge(
    const bf16* __restrict__ O0, const bf16* __restrict__ O1,
    const float* __restrict__ L0, const float* __restrict__ M0,
    const float* __restrict__ L1, const float* __restrict__ M1,
    bf16* __restrict__ AO) {
  const int i = blockIdx.x * blockDim.x + threadIdx.x;
  const int e = i * 8;                // 8 bf16 per thread, within one head
  const int row = e >> 10;            // token 0..4095
  const int b = row >> 11, s = row & 2047;
  const int h = (e >> 6) & 15;
  const int lmi = (b * NH + h) * S_LEN + s;
  const float m0 = M0[lmi], m1 = M1[lmi];
  const float m = fmaxf(m0, m1);
  const float a0 = exp2f(m0 - m), a1 = exp2f(m1 - m);
  const float inv = 1.0f / (a0 * L0[lmi] + a1 * L1[lmi]);
  const float f0 = a0 * inv, f1 = a1 * inv;
  bf16x8 v0 = *reinterpret_cast<const bf16x8*>(O0 + e);
  bf16x8 v1 = *reinterpret_cast<const bf16x8*>(O1 + e);
  bf16x8 o;
#pragma unroll
  for (int j = 0; j < 8; ++j)
    o[j] = (bf16)(f0 * (float)v0[j] + f1 * (float)v1[j]);
  *reinterpret_cast<bf16x8*>(AO + e) = o;
}

// ---------------------------------------------------------------- out proj
__global__ __launch_bounds__(256) void gemm_out(
    const bf16* __restrict__ A, const bf16* __restrict__ W,
    const float* __restrict__ bias, float* __restrict__ C) {
  __shared__ char smem[65536];
  const int m0 = blockIdx.y * 128, n0 = blockIdx.x * 128;
  const int tid = threadIdx.x, lane = tid & 63, wid = tid >> 6;
  const int wr = (wid >> 1) * 64, wc = (wid & 1) * 64;
  const int scb = 16 * ((lane & 7) ^ (lane >> 3));
  const int lr8 = lane >> 3;
  f32x4 acc[4][4] = {};

  auto STAGE = [&](int bi, int k0) {
#pragma unroll
    for (int c = 0; c < 4; ++c) {
      const int chunk = wid * 4 + c;
      const int row = chunk * 8 + lr8;
      gld16((const char*)A + ((size_t)(m0 + row) * DM + k0) * 2 + scb,
            smem + bi * 32768 + chunk * 1024);
      gld16((const char*)W + ((size_t)(n0 + row) * DM + k0) * 2 + scb,
            smem + bi * 32768 + 16384 + chunk * 1024);
    }
  };

  STAGE(0, 0);

  const int NK = DM / 64;
  for (int it = 0; it < NK; ++it) {
    if (it + 1 < NK) {
      STAGE((it + 1) & 1, (it + 1) * 64);
      asm volatile("s_waitcnt vmcnt(8)" ::: "memory");
    } else {
      asm volatile("s_waitcnt vmcnt(0)" ::: "memory");
    }
    __builtin_amdgcn_s_barrier();
    asm volatile("" ::: "memory");
    const char* As = smem + (it & 1) * 32768;
    const char* Bs = As + 16384;
#pragma unroll
    for (int kk = 0; kk < 2; ++kk) {
      bf16x8 af[4], bfr[4];
#pragma unroll
      for (int i = 0; i < 4; ++i) {
        const int ar = wr + i * 16 + (lane & 15);
        af[i] = *reinterpret_cast<const bf16x8*>(
            As + ar * 128 + ((kk * 64 + 16 * (lane >> 4)) ^ ((ar & 7) << 4)));
        const int br = wc + i * 16 + (lane & 15);
        bfr[i] = *reinterpret_cast<const bf16x8*>(
            Bs + br * 128 + ((kk * 64 + 16 * (lane >> 4)) ^ ((br & 7) << 4)));
      }
      __builtin_amdgcn_s_setprio(1);
#pragma unroll
      for (int i = 0; i < 4; ++i)
#pragma unroll
        for (int j = 0; j < 4; ++j)
          acc[i][j] = __builtin_amdgcn_mfma_f32_16x16x32_bf16(af[i], bfr[j], acc[i][j], 0, 0, 0);
      __builtin_amdgcn_s_setprio(0);
    }
    asm volatile("" ::: "memory");
    __builtin_amdgcn_s_barrier();
  }

  const int r4 = (lane >> 4) * 4;
#pragma unroll
  for (int i = 0; i < 4; ++i) {
    const int mrow = m0 + wr + i * 16 + r4;
#pragma unroll
    for (int j = 0; j < 4; ++j) {
      const int n = n0 + wc + j * 16 + (lane & 15);
      const float bs = bias[n];
#pragma unroll
      for (int r = 0; r < 4; ++r) C[(size_t)(mrow + r) * DM + n] = acc[i][j][r] + bs;
    }
  }
}

// ---------------------------------------------------------------- launcher
extern "C" void kernel_launch(void* const* d_in, const int* in_sizes, int n_in,
                              void* d_out, int out_size, void* d_ws, size_t ws_size,
                              hipStream_t stream) {
  const float* x = (const float*)d_in[0];
  const float* Wq = (const float*)d_in[2];
  const float* bq = (const float*)d_in[3];
  const float* Wk = (const float*)d_in[4];
  const float* bk = (const float*)d_in[5];
  const float* Wv = (const float*)d_in[6];
  const float* bv = (const float*)d_in[7];
  const float* Wo = (const float*)d_in[8];
  const float* bo = (const float*)d_in[9];

  char* ws = (char*)d_ws;  // 48 MB total, regions reused across phases
  bf16* xb  = (bf16*)(ws);
  bf16* wqb = (bf16*)(ws + (8u << 20));
  bf16* wkb = (bf16*)(ws + (10u << 20));
  bf16* wvb = (bf16*)(ws + (12u << 20));
  bf16* wob = (bf16*)(ws + (14u << 20));
  bf16* Qw  = (bf16*)(ws + (16u << 20));
  bf16* Kw  = (bf16*)(ws + (24u << 20));
  bf16* Vtw = (bf16*)(ws + (32u << 20));
  bf16* AO  = (bf16*)(ws + (40u << 20));

  // attn partial buffers (reuse dead regions):
  bf16* O0p = (bf16*)(ws);                         // 8MB in xb slot
  bf16* O1p = AO;                                  // 8MB in AO slot (merged in place)
  float* L0 = (float*)(ws + (8u << 20));           // 256KB each, in wqb slot
  float* M0 = (float*)(ws + (8u << 20) + 262144);
  float* L1 = (float*)(ws + (8u << 20) + 524288);
  float* M1 = (float*)(ws + (8u << 20) + 786432);

  cvt_all<<<8192, 256, 0, stream>>>(x, Wq, Wk, Wv, Wo, xb, wqb, wkb, wvb, wob);

  gemm_qkv<<<dim3(DM / 128, MTOK / 128, 3), 256, 0, stream>>>(
      xb, wqb, wkb, wvb, bq, bk, bv, Qw, Kw, Vtw);
  attn_fwd<<<dim3(1024), 256, 0, stream>>>(Qw, Kw, Vtw, O0p, O1p, L0, M0, L1, M1);
  attn_merge<<<dim3(2048), 256, 0, stream>>>(O0p, O1p, L0, M0, L1, M1, AO);
  gemm_out<<<dim3(DM / 128, MTOK / 128), 256, 0, stream>>>(AO, wob, bo, (float*)d_out);
}